// Round 2
// baseline (311.094 us; speedup 1.0000x reference)
//
#include <hip/hip_runtime.h>

// GAT edge-average forward, factored + CSR-grouped by tgt (no output atomics):
//   A = x @ Wf[:, :64]^T            [N,64]  (ws)
//   B = x @ Wf[:, 64:]^T + bf       [N,64]  (stored in d_out, overwritten later)
//   c = x @ Ww[0, :64]              [N]
//   d = x @ Ww[0, 64:] + bw         [N]
//   CSR: deg/hist -> exclusive scan -> scatter src ids sorted by tgt
//   gather: wave=node t, lane=dim: acc += relu(A[s]+B[t]) * (c[s]+d[t]); out = acc/(sum a + eps)

__global__ __launch_bounds__(256) void gat_precompute(
    const float* __restrict__ x, const float* __restrict__ Wf,
    const float* __restrict__ Ww, const float* __restrict__ bf,
    const float* __restrict__ bw,
    float* __restrict__ A, float* __restrict__ B,
    float* __restrict__ cg, float* __restrict__ dg, int N)
{
    __shared__ float w2[64][132];
    __shared__ float xs[64][68];
    __shared__ float ww[128];
    __shared__ float bfs[64];

    const int tid = threadIdx.x;
    for (int f = tid; f < 64 * 128; f += 256) {
        int d  = f >> 7;
        int kk = f & 127;
        w2[kk & 63][(kk >> 6) * 64 + d] = Wf[f];
    }
    if (tid < 128) ww[tid] = Ww[tid];
    if (tid < 64)  bfs[tid] = bf[tid];

    const int n0 = blockIdx.x << 6;
    for (int i = tid; i < 64 * 64; i += 256) {
        int nl = i >> 6, k = i & 63;
        int n = n0 + nl;
        xs[k][nl] = (n < N) ? x[(size_t)n * 64 + k] : 0.f;
    }
    __syncthreads();

    const int ti = tid & 15, tj = tid >> 4;
    float acc[4][8];
#pragma unroll
    for (int i = 0; i < 4; ++i)
#pragma unroll
        for (int j = 0; j < 8; ++j) acc[i][j] = 0.f;

#pragma unroll 4
    for (int k = 0; k < 64; ++k) {
        const float4 xv = *(const float4*)&xs[k][ti * 4];
        const float4 w0 = *(const float4*)&w2[k][tj * 8];
        const float4 w1 = *(const float4*)&w2[k][tj * 8 + 4];
        const float xa[4] = {xv.x, xv.y, xv.z, xv.w};
        const float wa[8] = {w0.x, w0.y, w0.z, w0.w, w1.x, w1.y, w1.z, w1.w};
#pragma unroll
        for (int i = 0; i < 4; ++i)
#pragma unroll
            for (int j = 0; j < 8; ++j)
                acc[i][j] = fmaf(xa[i], wa[j], acc[i][j]);
    }

#pragma unroll
    for (int i = 0; i < 4; ++i) {
        const int n = n0 + ti * 4 + i;
        if (n < N) {
            if (tj < 8) {
#pragma unroll
                for (int j = 0; j < 8; ++j)
                    A[(size_t)n * 64 + tj * 8 + j] = acc[i][j];
            } else {
#pragma unroll
                for (int j = 0; j < 8; ++j) {
                    int d2 = (tj - 8) * 8 + j;
                    B[(size_t)n * 64 + d2] = acc[i][j] + bfs[d2];
                }
            }
        }
    }

    if (tid < 64) {
        const int n = n0 + tid;
        if (n < N) {
            float sc = 0.f, sd = 0.f;
            for (int k = 0; k < 64; ++k) {
                const float xv = xs[k][tid];
                sc = fmaf(xv, ww[k], sc);
                sd = fmaf(xv, ww[64 + k], sd);
            }
            cg[n] = sc;
            dg[n] = sd + bw[0];
        }
    }
}

__global__ __launch_bounds__(256) void gat_hist(
    const int* __restrict__ tgt, int* __restrict__ deg, int E)
{
    const int stride = gridDim.x * blockDim.x;
    for (int e = blockIdx.x * blockDim.x + threadIdx.x; e < E; e += stride)
        atomicAdd(&deg[tgt[e]], 1);
}

__global__ __launch_bounds__(1024) void gat_scan(
    const int* __restrict__ deg, int* __restrict__ starts,
    int* __restrict__ cursor, int N)
{
    __shared__ int part[1024];
    const int T = 1024;
    const int chunk = (N + T - 1) / T;
    const int lo = threadIdx.x * chunk;
    const int hi = min(lo + chunk, N);
    int s = 0;
    for (int i = lo; i < hi; ++i) s += deg[i];
    part[threadIdx.x] = s;
    __syncthreads();
    for (int off = 1; off < T; off <<= 1) {
        int v = (threadIdx.x >= off) ? part[threadIdx.x - off] : 0;
        __syncthreads();
        part[threadIdx.x] += v;
        __syncthreads();
    }
    int base = (threadIdx.x > 0) ? part[threadIdx.x - 1] : 0;  // exclusive
    for (int i = lo; i < hi; ++i) {
        starts[i] = base;
        cursor[i] = base;
        base += deg[i];
    }
    if (threadIdx.x == T - 1) starts[N] = base;  // == E
}

__global__ __launch_bounds__(256) void gat_scatter(
    const int* __restrict__ src, const int* __restrict__ tgt,
    int* __restrict__ cursor, int* __restrict__ sorted_src, int E)
{
    const int stride = gridDim.x * blockDim.x;
    for (int e = blockIdx.x * blockDim.x + threadIdx.x; e < E; e += stride) {
        const int t = tgt[e];
        const int p = atomicAdd(&cursor[t], 1);
        sorted_src[p] = src[e];
    }
}

__global__ __launch_bounds__(256) void gat_gather(
    const int* __restrict__ starts, const int* __restrict__ sorted_src,
    const float* __restrict__ A, const float* __restrict__ B,
    const float* __restrict__ cg, const float* __restrict__ dg,
    float* __restrict__ out, int N)
{
    const int d = threadIdx.x & 63;
    const int node = blockIdx.x * (blockDim.x >> 6) + (threadIdx.x >> 6);
    if (node >= N) return;
    const int e0 = starts[node];
    const int e1 = starts[node + 1];
    const float Bt  = B[(size_t)node * 64 + d];
    const float dgt = dg[node];
    float acc = 0.f, asum = 0.f;
    for (int e = e0; e < e1; ++e) {
        const int s   = sorted_src[e];
        const float a = cg[s] + dgt;
        const float y = fmaxf(A[(size_t)s * 64 + d] + Bt, 0.f);
        acc = fmaf(y, a, acc);
        asum += a;
    }
    out[(size_t)node * 64 + d] = acc / (asum + 1e-6f);
}

extern "C" void kernel_launch(void* const* d_in, const int* in_sizes, int n_in,
                              void* d_out, int out_size, void* d_ws, size_t ws_size,
                              hipStream_t stream)
{
    // setup_inputs order: x, adj, src, tgt, Msrc, Wf, bf, Ww, bw
    const float* x   = (const float*)d_in[0];
    const int*   src = (const int*)d_in[2];
    const int*   tgt = (const int*)d_in[3];
    const float* Wf  = (const float*)d_in[5];
    const float* bf  = (const float*)d_in[6];
    const float* Ww  = (const float*)d_in[7];
    const float* bw  = (const float*)d_in[8];

    const int N = in_sizes[0] / 64;
    const int E = in_sizes[2];
    float* out = (float*)d_out;

    // B lives in d_out: each B row is read only by its own node's wave in
    // gat_gather, in-thread before that wave overwrites it with the output.
    float* B = out;

    float* A          = (float*)d_ws;                 // N*64 f32
    float* cg         = A + (size_t)N * 64;           // N
    float* dg         = cg + N;                       // N
    int*   deg        = (int*)(dg + N);               // N
    int*   starts     = deg + N;                      // N+1
    int*   cursor     = starts + N + 1;               // N
    int*   sorted_src = cursor + N;                   // E
    // total ws: (64+3)*N*4 + (2N+1)*4 + E*4  ~= 17.0 MB

    hipMemsetAsync(deg, 0, (size_t)N * sizeof(int), stream);

    const int nb1 = (N + 63) / 64;
    gat_precompute<<<nb1, 256, 0, stream>>>(x, Wf, Ww, bf, bw, A, B, cg, dg, N);
    gat_hist<<<1024, 256, 0, stream>>>(tgt, deg, E);
    gat_scan<<<1, 1024, 0, stream>>>(deg, starts, cursor, N);
    gat_scatter<<<1024, 256, 0, stream>>>(src, tgt, cursor, sorted_src, E);
    const int nb2 = (N + 3) / 4;  // 4 waves (nodes) per 256-thread block
    gat_gather<<<nb2, 256, 0, stream>>>(starts, sorted_src, A, B, cg, dg, out, N);
}

// Round 3
// 218.550 us; speedup vs baseline: 1.4234x; 1.4234x over previous
//
#include <hip/hip_runtime.h>

// GAT edge-average forward, factored + CSR-grouped by tgt (no output atomics):
//   A = x @ Wf[:, :64]^T            [N,64]  (ws)
//   B = x @ Wf[:, 64:]^T + bf       [N,64]  (stored in d_out, overwritten later)
//   c = x @ Ww[0, :64]              [N]
//   d = x @ Ww[0, 64:] + bw         [N]
//   CSR: deg/hist -> 3-phase parallel exclusive scan -> scatter src by tgt
//   gather: wave=node t, lane=dim: acc += relu(A[s]+B[t]) * (c[s]+d[t]); out = acc/(sum a + eps)

__global__ __launch_bounds__(256) void gat_precompute(
    const float* __restrict__ x, const float* __restrict__ Wf,
    const float* __restrict__ Ww, const float* __restrict__ bf,
    const float* __restrict__ bw,
    float* __restrict__ A, float* __restrict__ B,
    float* __restrict__ cg, float* __restrict__ dg, int N)
{
    __shared__ float w2[64][132];
    __shared__ float xs[64][68];
    __shared__ float ww[128];
    __shared__ float bfs[64];

    const int tid = threadIdx.x;
    for (int f = tid; f < 64 * 128; f += 256) {
        int d  = f >> 7;
        int kk = f & 127;
        w2[kk & 63][(kk >> 6) * 64 + d] = Wf[f];
    }
    if (tid < 128) ww[tid] = Ww[tid];
    if (tid < 64)  bfs[tid] = bf[tid];

    const int n0 = blockIdx.x << 6;
    for (int i = tid; i < 64 * 64; i += 256) {
        int nl = i >> 6, k = i & 63;
        int n = n0 + nl;
        xs[k][nl] = (n < N) ? x[(size_t)n * 64 + k] : 0.f;
    }
    __syncthreads();

    const int ti = tid & 15, tj = tid >> 4;
    float acc[4][8];
#pragma unroll
    for (int i = 0; i < 4; ++i)
#pragma unroll
        for (int j = 0; j < 8; ++j) acc[i][j] = 0.f;

#pragma unroll 4
    for (int k = 0; k < 64; ++k) {
        const float4 xv = *(const float4*)&xs[k][ti * 4];
        const float4 w0 = *(const float4*)&w2[k][tj * 8];
        const float4 w1 = *(const float4*)&w2[k][tj * 8 + 4];
        const float xa[4] = {xv.x, xv.y, xv.z, xv.w};
        const float wa[8] = {w0.x, w0.y, w0.z, w0.w, w1.x, w1.y, w1.z, w1.w};
#pragma unroll
        for (int i = 0; i < 4; ++i)
#pragma unroll
            for (int j = 0; j < 8; ++j)
                acc[i][j] = fmaf(xa[i], wa[j], acc[i][j]);
    }

#pragma unroll
    for (int i = 0; i < 4; ++i) {
        const int n = n0 + ti * 4 + i;
        if (n < N) {
            if (tj < 8) {
#pragma unroll
                for (int j = 0; j < 8; ++j)
                    A[(size_t)n * 64 + tj * 8 + j] = acc[i][j];
            } else {
#pragma unroll
                for (int j = 0; j < 8; ++j) {
                    int d2 = (tj - 8) * 8 + j;
                    B[(size_t)n * 64 + d2] = acc[i][j] + bfs[d2];
                }
            }
        }
    }

    if (tid < 64) {
        const int n = n0 + tid;
        if (n < N) {
            float sc = 0.f, sd = 0.f;
            for (int k = 0; k < 64; ++k) {
                const float xv = xs[k][tid];
                sc = fmaf(xv, ww[k], sc);
                sd = fmaf(xv, ww[64 + k], sd);
            }
            cg[n] = sc;
            dg[n] = sd + bw[0];
        }
    }
}

__global__ __launch_bounds__(256) void gat_hist(
    const int* __restrict__ tgt, int* __restrict__ deg, int E)
{
    const int stride = gridDim.x * blockDim.x;
    for (int e = blockIdx.x * blockDim.x + threadIdx.x; e < E; e += stride)
        atomicAdd(&deg[tgt[e]], 1);
}

// Phase 1: per-block exclusive scan of deg -> starts (local), block total -> bsum
__global__ __launch_bounds__(256) void gat_scan1(
    const int* __restrict__ deg, int* __restrict__ starts,
    int* __restrict__ bsum, int N)
{
    __shared__ int tmp[256];
    const int i = blockIdx.x * 256 + threadIdx.x;
    const int v = (i < N) ? deg[i] : 0;
    tmp[threadIdx.x] = v;
    __syncthreads();
#pragma unroll
    for (int off = 1; off < 256; off <<= 1) {
        const int add = (threadIdx.x >= off) ? tmp[threadIdx.x - off] : 0;
        __syncthreads();
        tmp[threadIdx.x] += add;
        __syncthreads();
    }
    if (i < N) starts[i] = tmp[threadIdx.x] - v;          // exclusive within block
    if (threadIdx.x == 255) bsum[blockIdx.x] = tmp[255];  // block total
}

// Phase 2: single-block exclusive scan of the <=1024 block sums, in place
__global__ __launch_bounds__(1024) void gat_scan2(int* __restrict__ bsum, int nb)
{
    __shared__ int tmp[1024];
    const int v = (threadIdx.x < nb) ? bsum[threadIdx.x] : 0;
    tmp[threadIdx.x] = v;
    __syncthreads();
#pragma unroll
    for (int off = 1; off < 1024; off <<= 1) {
        const int add = (threadIdx.x >= off) ? tmp[threadIdx.x - off] : 0;
        __syncthreads();
        tmp[threadIdx.x] += add;
        __syncthreads();
    }
    if (threadIdx.x < nb) bsum[threadIdx.x] = tmp[threadIdx.x] - v;  // exclusive
}

// Phase 3: add block offset; materialize starts + cursor; starts[N] = E
__global__ __launch_bounds__(256) void gat_scan3(
    int* __restrict__ starts, int* __restrict__ cursor,
    const int* __restrict__ bsum, int N, int E)
{
    const int i = blockIdx.x * 256 + threadIdx.x;
    if (i < N) {
        const int s = starts[i] + bsum[blockIdx.x];
        starts[i] = s;
        cursor[i] = s;
    }
    if (i == 0) starts[N] = E;
}

__global__ __launch_bounds__(256) void gat_scatter(
    const int* __restrict__ src, const int* __restrict__ tgt,
    int* __restrict__ cursor, int* __restrict__ sorted_src, int E)
{
    const int stride = gridDim.x * blockDim.x;
    for (int e = blockIdx.x * blockDim.x + threadIdx.x; e < E; e += stride) {
        const int t = tgt[e];
        const int p = atomicAdd(&cursor[t], 1);
        sorted_src[p] = src[e];
    }
}

__global__ __launch_bounds__(256) void gat_gather(
    const int* __restrict__ starts, const int* __restrict__ sorted_src,
    const float* __restrict__ A, const float* __restrict__ B,
    const float* __restrict__ cg, const float* __restrict__ dg,
    float* __restrict__ out, int N)
{
    const int d = threadIdx.x & 63;
    const int node = blockIdx.x * (blockDim.x >> 6) + (threadIdx.x >> 6);
    if (node >= N) return;
    const int e0 = starts[node];
    const int e1 = starts[node + 1];
    const float Bt  = B[(size_t)node * 64 + d];
    const float dgt = dg[node];
    float acc = 0.f, asum = 0.f;
    for (int e = e0; e < e1; ++e) {
        const int s   = sorted_src[e];
        const float a = cg[s] + dgt;
        const float y = fmaxf(A[(size_t)s * 64 + d] + Bt, 0.f);
        acc = fmaf(y, a, acc);
        asum += a;
    }
    out[(size_t)node * 64 + d] = acc / (asum + 1e-6f);
}

extern "C" void kernel_launch(void* const* d_in, const int* in_sizes, int n_in,
                              void* d_out, int out_size, void* d_ws, size_t ws_size,
                              hipStream_t stream)
{
    // setup_inputs order: x, adj, src, tgt, Msrc, Wf, bf, Ww, bw
    const float* x   = (const float*)d_in[0];
    const int*   src = (const int*)d_in[2];
    const int*   tgt = (const int*)d_in[3];
    const float* Wf  = (const float*)d_in[5];
    const float* bf  = (const float*)d_in[6];
    const float* Ww  = (const float*)d_in[7];
    const float* bw  = (const float*)d_in[8];

    const int N = in_sizes[0] / 64;
    const int E = in_sizes[2];
    float* out = (float*)d_out;

    // B lives in d_out: each B row is read only by its own node's wave in
    // gat_gather, in-thread before that wave overwrites it with the output.
    float* B = out;

    float* A          = (float*)d_ws;                 // N*64 f32
    float* cg         = A + (size_t)N * 64;           // N
    float* dg         = cg + N;                       // N
    int*   deg        = (int*)(dg + N);               // N
    int*   starts     = deg + N;                      // N+1
    int*   cursor     = starts + N + 1;               // N
    int*   sorted_src = cursor + N;                   // E
    int*   bsum       = sorted_src + E;               // <=1024
    // total ws: ~17 MB

    hipMemsetAsync(deg, 0, (size_t)N * sizeof(int), stream);

    const int nb1 = (N + 63) / 64;
    gat_precompute<<<nb1, 256, 0, stream>>>(x, Wf, Ww, bf, bw, A, B, cg, dg, N);
    gat_hist<<<1024, 256, 0, stream>>>(tgt, deg, E);
    const int nbs = (N + 255) / 256;   // 196 blocks; must be <= 1024
    gat_scan1<<<nbs, 256, 0, stream>>>(deg, starts, bsum, N);
    gat_scan2<<<1, 1024, 0, stream>>>(bsum, nbs);
    gat_scan3<<<nbs, 256, 0, stream>>>(starts, cursor, bsum, N, E);
    gat_scatter<<<1024, 256, 0, stream>>>(src, tgt, cursor, sorted_src, E);
    const int nb2 = (N + 3) / 4;  // 4 waves (nodes) per 256-thread block
    gat_gather<<<nb2, 256, 0, stream>>>(starts, sorted_src, A, B, cg, dg, out, N);
}

// Round 4
// 156.426 us; speedup vs baseline: 1.9888x; 1.3971x over previous
//
#include <hip/hip_runtime.h>
#include <hip/hip_bf16.h>

// GAT edge-average forward, factored + CSR-grouped by tgt (no output atomics):
//   A = x @ Wf[:, :64]^T            [N,64]  bf16 in ws (halves gather traffic)
//   B = x @ Wf[:, 64:]^T + bf       [N,64]  f32 in ws
//   c = x @ Ww[0, :64]              [N]
//   d = x @ Ww[0, 64:] + bw         [N]
//   CSR: deg/hist (fused into precompute launch) -> 3-phase scan -> scatter
//   gather: wave=node t, lane=dim, unroll x4: acc += relu(A[s]+B[t])*(c[s]+d[t])

__global__ __launch_bounds__(256) void gat_pre_hist(
    const float* __restrict__ x, const float* __restrict__ Wf,
    const float* __restrict__ Ww, const float* __restrict__ bf,
    const float* __restrict__ bw,
    __hip_bfloat16* __restrict__ A16, float* __restrict__ B,
    float* __restrict__ cg, float* __restrict__ dg, int N,
    const int* __restrict__ tgt, int* __restrict__ deg, int E, int nb1)
{
    __shared__ float w2[64][132];
    __shared__ float xs[64][68];
    __shared__ float ww[128];
    __shared__ float bfs[64];

    const int tid = threadIdx.x;

    if (blockIdx.x >= nb1) {
        // histogram of tgt (independent of the GEMM work; hides under it)
        const int bid = blockIdx.x - nb1;
        const int nbh = gridDim.x - nb1;
        const int stride = nbh * 256;
        for (int e = bid * 256 + tid; e < E; e += stride)
            atomicAdd(&deg[tgt[e]], 1);
        return;
    }

    for (int f = tid; f < 64 * 128; f += 256) {
        int d  = f >> 7;
        int kk = f & 127;
        w2[kk & 63][(kk >> 6) * 64 + d] = Wf[f];
    }
    if (tid < 128) ww[tid] = Ww[tid];
    if (tid < 64)  bfs[tid] = bf[tid];

    const int n0 = blockIdx.x << 6;
    for (int i = tid; i < 64 * 64; i += 256) {
        int nl = i >> 6, k = i & 63;
        int n = n0 + nl;
        xs[k][nl] = (n < N) ? x[(size_t)n * 64 + k] : 0.f;
    }
    __syncthreads();

    const int ti = tid & 15, tj = tid >> 4;
    float acc[4][8];
#pragma unroll
    for (int i = 0; i < 4; ++i)
#pragma unroll
        for (int j = 0; j < 8; ++j) acc[i][j] = 0.f;

#pragma unroll 4
    for (int k = 0; k < 64; ++k) {
        const float4 xv = *(const float4*)&xs[k][ti * 4];
        const float4 w0 = *(const float4*)&w2[k][tj * 8];
        const float4 w1 = *(const float4*)&w2[k][tj * 8 + 4];
        const float xa[4] = {xv.x, xv.y, xv.z, xv.w};
        const float wa[8] = {w0.x, w0.y, w0.z, w0.w, w1.x, w1.y, w1.z, w1.w};
#pragma unroll
        for (int i = 0; i < 4; ++i)
#pragma unroll
            for (int j = 0; j < 8; ++j)
                acc[i][j] = fmaf(xa[i], wa[j], acc[i][j]);
    }

#pragma unroll
    for (int i = 0; i < 4; ++i) {
        const int n = n0 + ti * 4 + i;
        if (n < N) {
            if (tj < 8) {
#pragma unroll
                for (int j = 0; j < 8; ++j)
                    A16[(size_t)n * 64 + tj * 8 + j] = __float2bfloat16(acc[i][j]);
            } else {
#pragma unroll
                for (int j = 0; j < 8; ++j) {
                    int d2 = (tj - 8) * 8 + j;
                    B[(size_t)n * 64 + d2] = acc[i][j] + bfs[d2];
                }
            }
        }
    }

    if (tid < 64) {
        const int n = n0 + tid;
        if (n < N) {
            float sc = 0.f, sd = 0.f;
            for (int k = 0; k < 64; ++k) {
                const float xv = xs[k][tid];
                sc = fmaf(xv, ww[k], sc);
                sd = fmaf(xv, ww[64 + k], sd);
            }
            cg[n] = sc;
            dg[n] = sd + bw[0];
        }
    }
}

// Phase 1: per-block exclusive scan of deg -> starts (local), block total -> bsum
__global__ __launch_bounds__(256) void gat_scan1(
    const int* __restrict__ deg, int* __restrict__ starts,
    int* __restrict__ bsum, int N)
{
    __shared__ int tmp[256];
    const int i = blockIdx.x * 256 + threadIdx.x;
    const int v = (i < N) ? deg[i] : 0;
    tmp[threadIdx.x] = v;
    __syncthreads();
#pragma unroll
    for (int off = 1; off < 256; off <<= 1) {
        const int add = (threadIdx.x >= off) ? tmp[threadIdx.x - off] : 0;
        __syncthreads();
        tmp[threadIdx.x] += add;
        __syncthreads();
    }
    if (i < N) starts[i] = tmp[threadIdx.x] - v;
    if (threadIdx.x == 255) bsum[blockIdx.x] = tmp[255];
}

// Phase 2: single-block exclusive scan of the <=1024 block sums, in place
__global__ __launch_bounds__(1024) void gat_scan2(int* __restrict__ bsum, int nb)
{
    __shared__ int tmp[1024];
    const int v = (threadIdx.x < nb) ? bsum[threadIdx.x] : 0;
    tmp[threadIdx.x] = v;
    __syncthreads();
#pragma unroll
    for (int off = 1; off < 1024; off <<= 1) {
        const int add = (threadIdx.x >= off) ? tmp[threadIdx.x - off] : 0;
        __syncthreads();
        tmp[threadIdx.x] += add;
        __syncthreads();
    }
    if (threadIdx.x < nb) bsum[threadIdx.x] = tmp[threadIdx.x] - v;
}

// Phase 3: add block offset; materialize starts + cursor; starts[N] = E
__global__ __launch_bounds__(256) void gat_scan3(
    int* __restrict__ starts, int* __restrict__ cursor,
    const int* __restrict__ bsum, int N, int E)
{
    const int i = blockIdx.x * 256 + threadIdx.x;
    if (i < N) {
        const int s = starts[i] + bsum[blockIdx.x];
        starts[i] = s;
        cursor[i] = s;
    }
    if (i == 0) starts[N] = E;
}

__global__ __launch_bounds__(256) void gat_scatter(
    const int* __restrict__ src, const int* __restrict__ tgt,
    int* __restrict__ cursor, int* __restrict__ sorted_src, int E)
{
    const int stride = gridDim.x * blockDim.x;
    for (int e = blockIdx.x * blockDim.x + threadIdx.x; e < E; e += stride) {
        const int t = tgt[e];
        const int p = atomicAdd(&cursor[t], 1);
        sorted_src[p] = src[e];
    }
}

__global__ __launch_bounds__(256) void gat_gather(
    const int* __restrict__ starts, const int* __restrict__ sorted_src,
    const __hip_bfloat16* __restrict__ A16, const float* __restrict__ B,
    const float* __restrict__ cg, const float* __restrict__ dg,
    float* __restrict__ out, int N)
{
    const int d = threadIdx.x & 63;
    const int node = blockIdx.x * (blockDim.x >> 6) + (threadIdx.x >> 6);
    if (node >= N) return;
    const int e0 = starts[node];
    const int e1 = starts[node + 1];
    const float Bt  = B[(size_t)node * 64 + d];
    const float dgt = dg[node];
    float acc = 0.f, asum = 0.f;

    int e = e0;
    // unroll x4: 4 independent gather chains in flight per wave
    for (; e + 3 < e1; e += 4) {
        const int s0 = sorted_src[e];
        const int s1 = sorted_src[e + 1];
        const int s2 = sorted_src[e + 2];
        const int s3 = sorted_src[e + 3];
        const float a0 = cg[s0] + dgt;
        const float a1 = cg[s1] + dgt;
        const float a2 = cg[s2] + dgt;
        const float a3 = cg[s3] + dgt;
        const float x0 = __bfloat162float(A16[(size_t)s0 * 64 + d]);
        const float x1 = __bfloat162float(A16[(size_t)s1 * 64 + d]);
        const float x2 = __bfloat162float(A16[(size_t)s2 * 64 + d]);
        const float x3 = __bfloat162float(A16[(size_t)s3 * 64 + d]);
        acc = fmaf(fmaxf(x0 + Bt, 0.f), a0, acc);
        acc = fmaf(fmaxf(x1 + Bt, 0.f), a1, acc);
        acc = fmaf(fmaxf(x2 + Bt, 0.f), a2, acc);
        acc = fmaf(fmaxf(x3 + Bt, 0.f), a3, acc);
        asum += (a0 + a1) + (a2 + a3);
    }
    for (; e < e1; ++e) {
        const int s   = sorted_src[e];
        const float a = cg[s] + dgt;
        const float xv = __bfloat162float(A16[(size_t)s * 64 + d]);
        acc = fmaf(fmaxf(xv + Bt, 0.f), a, acc);
        asum += a;
    }
    out[(size_t)node * 64 + d] = acc / (asum + 1e-6f);
}

extern "C" void kernel_launch(void* const* d_in, const int* in_sizes, int n_in,
                              void* d_out, int out_size, void* d_ws, size_t ws_size,
                              hipStream_t stream)
{
    // setup_inputs order: x, adj, src, tgt, Msrc, Wf, bf, Ww, bw
    const float* x   = (const float*)d_in[0];
    const int*   src = (const int*)d_in[2];
    const int*   tgt = (const int*)d_in[3];
    const float* Wf  = (const float*)d_in[5];
    const float* bf  = (const float*)d_in[6];
    const float* Ww  = (const float*)d_in[7];
    const float* bw  = (const float*)d_in[8];

    const int N = in_sizes[0] / 64;
    const int E = in_sizes[2];
    float* out = (float*)d_out;

    __hip_bfloat16* A16 = (__hip_bfloat16*)d_ws;          // N*64 bf16 (6.4 MB)
    float* B          = (float*)(A16 + (size_t)N * 64);   // N*64 f32  (12.8 MB)
    float* cg         = B + (size_t)N * 64;               // N
    float* dg         = cg + N;                           // N
    int*   deg        = (int*)(dg + N);                   // N
    int*   starts     = deg + N;                          // N+1
    int*   cursor     = starts + N + 1;                   // N
    int*   sorted_src = cursor + N;                       // E
    int*   bsum       = sorted_src + E;                   // <=1024
    // total ws: ~23.5 MB

    hipMemsetAsync(deg, 0, (size_t)N * sizeof(int), stream);

    const int nb1 = (N + 63) / 64;
    const int nbh = 1024;  // hist blocks appended to the precompute grid
    gat_pre_hist<<<nb1 + nbh, 256, 0, stream>>>(x, Wf, Ww, bf, bw, A16, B, cg, dg, N,
                                                tgt, deg, E, nb1);
    const int nbs = (N + 255) / 256;   // must be <= 1024
    gat_scan1<<<nbs, 256, 0, stream>>>(deg, starts, bsum, N);
    gat_scan2<<<1, 1024, 0, stream>>>(bsum, nbs);
    gat_scan3<<<nbs, 256, 0, stream>>>(starts, cursor, bsum, N, E);
    gat_scatter<<<1024, 256, 0, stream>>>(src, tgt, cursor, sorted_src, E);
    const int nb2 = (N + 3) / 4;  // 4 waves (nodes) per 256-thread block
    gat_gather<<<nb2, 256, 0, stream>>>(starts, sorted_src, A16, B, cg, dg, out, N);
}

// Round 6
// 95.679 us; speedup vs baseline: 3.2514x; 1.6349x over previous
//
#include <hip/hip_runtime.h>
#include <hip/hip_bf16.h>

// GAT edge-average forward, factored + CSR via atomic-free bucketed counting sort:
//   A = x @ Wf[:, :64]^T            [N,64]  bf16 in ws
//   B = x @ Wf[:, 64:]^T + bf       [N,64]  f32 in ws
//   c = x @ Ww[0, :64]              [N]
//   d = x @ Ww[0, 64:] + bw         [N]
//   CSR build (no global atomics):
//     hist:   counts[bucket][blk] via LDS histogram (bucket = tgt>>8, NB=196)
//     scan:   exclusive scan of counts (3-phase)
//     part:   (src,tgt) pairs scattered to bucket regions (pairs in d_out)
//     bsort:  per-bucket LDS counting sort -> starts[], sorted_src[]
//   gather: wave=node, lane=dim, unroll x4: acc += relu(A[s]+B[t])*(c[s]+d[t])

#define NBLK 200   // edge-chunk blocks for hist/partition

__global__ __launch_bounds__(256) void gat_pre_hist(
    const float* __restrict__ x, const float* __restrict__ Wf,
    const float* __restrict__ Ww, const float* __restrict__ bf,
    const float* __restrict__ bw,
    __hip_bfloat16* __restrict__ A16, float* __restrict__ B,
    float* __restrict__ cg, float* __restrict__ dg, int N,
    const int* __restrict__ tgt, int* __restrict__ counts,
    int E, int NB, int chunk, int nb1)
{
    __shared__ float w2[64][132];
    __shared__ float xs[64][68];
    __shared__ float ww[128];
    __shared__ float bfs[64];
    __shared__ int   h[256];

    const int tid = threadIdx.x;

    if (blockIdx.x >= nb1) {
        // LDS-histogram of tgt buckets for this edge chunk; plain global writes
        const int k = blockIdx.x - nb1;          // 0..NBLK-1
        h[tid] = 0;
        __syncthreads();
        const int lo = k * chunk;
        const int hi = min(lo + chunk, E);
        for (int e = lo + tid; e < hi; e += 256)
            atomicAdd(&h[tgt[e] >> 8], 1);       // LDS atomic
        __syncthreads();
        if (tid < NB) counts[tid * NBLK + k] = h[tid];
        return;
    }

    for (int f = tid; f < 64 * 128; f += 256) {
        int d  = f >> 7;
        int kk = f & 127;
        w2[kk & 63][(kk >> 6) * 64 + d] = Wf[f];
    }
    if (tid < 128) ww[tid] = Ww[tid];
    if (tid < 64)  bfs[tid] = bf[tid];

    const int n0 = blockIdx.x << 6;
    for (int i = tid; i < 64 * 64; i += 256) {
        int nl = i >> 6, k = i & 63;
        int n = n0 + nl;
        xs[k][nl] = (n < N) ? x[(size_t)n * 64 + k] : 0.f;
    }
    __syncthreads();

    const int ti = tid & 15, tj = tid >> 4;
    float acc[4][8];
#pragma unroll
    for (int i = 0; i < 4; ++i)
#pragma unroll
        for (int j = 0; j < 8; ++j) acc[i][j] = 0.f;

#pragma unroll 4
    for (int k = 0; k < 64; ++k) {
        const float4 xv = *(const float4*)&xs[k][ti * 4];
        const float4 w0 = *(const float4*)&w2[k][tj * 8];
        const float4 w1 = *(const float4*)&w2[k][tj * 8 + 4];
        const float xa[4] = {xv.x, xv.y, xv.z, xv.w};
        const float wa[8] = {w0.x, w0.y, w0.z, w0.w, w1.x, w1.y, w1.z, w1.w};
#pragma unroll
        for (int i = 0; i < 4; ++i)
#pragma unroll
            for (int j = 0; j < 8; ++j)
                acc[i][j] = fmaf(xa[i], wa[j], acc[i][j]);
    }

#pragma unroll
    for (int i = 0; i < 4; ++i) {
        const int n = n0 + ti * 4 + i;
        if (n < N) {
            if (tj < 8) {
#pragma unroll
                for (int j = 0; j < 8; ++j)
                    A16[(size_t)n * 64 + tj * 8 + j] = __float2bfloat16(acc[i][j]);
            } else {
#pragma unroll
                for (int j = 0; j < 8; ++j) {
                    int d2 = (tj - 8) * 8 + j;
                    B[(size_t)n * 64 + d2] = acc[i][j] + bfs[d2];
                }
            }
        }
    }

    if (tid < 64) {
        const int n = n0 + tid;
        if (n < N) {
            float sc = 0.f, sd = 0.f;
            for (int k = 0; k < 64; ++k) {
                const float xv = xs[k][tid];
                sc = fmaf(xv, ww[k], sc);
                sd = fmaf(xv, ww[64 + k], sd);
            }
            cg[n] = sc;
            dg[n] = sd + bw[0];
        }
    }
}

// Phase 1: per-block exclusive scan (in -> out, may alias), block total -> bsum
__global__ __launch_bounds__(256) void gat_scan1(
    const int* __restrict__ in, int* __restrict__ out,
    int* __restrict__ bsum, int n)
{
    __shared__ int tmp[256];
    const int i = blockIdx.x * 256 + threadIdx.x;
    const int v = (i < n) ? in[i] : 0;
    tmp[threadIdx.x] = v;
    __syncthreads();
#pragma unroll
    for (int off = 1; off < 256; off <<= 1) {
        const int add = (threadIdx.x >= off) ? tmp[threadIdx.x - off] : 0;
        __syncthreads();
        tmp[threadIdx.x] += add;
        __syncthreads();
    }
    if (i < n) out[i] = tmp[threadIdx.x] - v;
    if (threadIdx.x == 255) bsum[blockIdx.x] = tmp[255];
}

// Phase 2: single-block exclusive scan of the <=1024 block sums, in place
__global__ __launch_bounds__(1024) void gat_scan2(int* __restrict__ bsum, int nb)
{
    __shared__ int tmp[1024];
    const int v = (threadIdx.x < nb) ? bsum[threadIdx.x] : 0;
    tmp[threadIdx.x] = v;
    __syncthreads();
#pragma unroll
    for (int off = 1; off < 1024; off <<= 1) {
        const int add = (threadIdx.x >= off) ? tmp[threadIdx.x - off] : 0;
        __syncthreads();
        tmp[threadIdx.x] += add;
        __syncthreads();
    }
    if (threadIdx.x < nb) bsum[threadIdx.x] = tmp[threadIdx.x] - v;
}

// Phase 3: add block offsets in place
__global__ __launch_bounds__(256) void gat_scan3(
    int* __restrict__ data, const int* __restrict__ bsum, int n)
{
    const int i = blockIdx.x * 256 + threadIdx.x;
    if (i < n) data[i] += bsum[blockIdx.x];
}

// Partition edges into tgt-buckets. psum[b*NBLK + k] = write base for block k,
// bucket b. LDS cursors only; pairs regions are per-(bucket,block) contiguous.
__global__ __launch_bounds__(256) void gat_partition(
    const int* __restrict__ src, const int* __restrict__ tgt,
    const int* __restrict__ psum, int2* __restrict__ pairs,
    int E, int NB, int chunk)
{
    __shared__ int cur[256];
    const int k = blockIdx.x;
    const int tid = threadIdx.x;
    if (tid < NB) cur[tid] = psum[tid * NBLK + k];
    __syncthreads();
    const int lo = k * chunk;
    const int hi = min(lo + chunk, E);
    for (int e = lo + tid; e < hi; e += 256) {
        const int t = tgt[e];
        const int s = src[e];
        const int pos = atomicAdd(&cur[t >> 8], 1);   // LDS atomic
        pairs[pos] = make_int2(s, t);
    }
}

// Per-bucket counting sort: block = bucket of 256 consecutive tgt values.
// Emits starts[] (global CSR offsets) and sorted_src[] (contiguous window).
__global__ __launch_bounds__(256) void gat_bucket_sort(
    const int2* __restrict__ pairs, const int* __restrict__ psum,
    int* __restrict__ starts, int* __restrict__ sorted_src,
    int N, int E, int NB)
{
    __shared__ int h[256];
    __shared__ int cur[256];
    const int b = blockIdx.x;
    const int tid = threadIdx.x;
    const int base = psum[b * NBLK];
    const int end  = (b + 1 < NB) ? psum[(b + 1) * NBLK] : E;

    h[tid] = 0;
    __syncthreads();
    for (int e = base + tid; e < end; e += 256)
        atomicAdd(&h[pairs[e].y & 255], 1);           // LDS atomic
    __syncthreads();
    const int v = h[tid];
#pragma unroll
    for (int off = 1; off < 256; off <<= 1) {
        const int add = (tid >= off) ? h[tid - off] : 0;
        __syncthreads();
        h[tid] += add;
        __syncthreads();
    }
    const int excl = h[tid] - v;                      // exclusive within bucket
    const int node = (b << 8) + tid;
    if (node < N) starts[node] = base + excl;
    if (b == NB - 1 && tid == 0) starts[N] = E;
    cur[tid] = base + excl;
    __syncthreads();
    for (int e = base + tid; e < end; e += 256) {
        const int2 p = pairs[e];
        const int pos = atomicAdd(&cur[p.y & 255], 1);  // LDS atomic
        sorted_src[pos] = p.x;
    }
}

__global__ __launch_bounds__(256) void gat_gather(
    const int* __restrict__ starts, const int* __restrict__ sorted_src,
    const __hip_bfloat16* __restrict__ A16, const float* __restrict__ B,
    const float* __restrict__ cg, const float* __restrict__ dg,
    float* __restrict__ out, int N)
{
    const int d = threadIdx.x & 63;
    const int node = blockIdx.x * (blockDim.x >> 6) + (threadIdx.x >> 6);
    if (node >= N) return;
    const int e0 = starts[node];
    const int e1 = starts[node + 1];
    const float Bt  = B[(size_t)node * 64 + d];
    const float dgt = dg[node];
    float acc = 0.f, asum = 0.f;

    int e = e0;
    for (; e + 3 < e1; e += 4) {
        const int s0 = sorted_src[e];
        const int s1 = sorted_src[e + 1];
        const int s2 = sorted_src[e + 2];
        const int s3 = sorted_src[e + 3];
        const float a0 = cg[s0] + dgt;
        const float a1 = cg[s1] + dgt;
        const float a2 = cg[s2] + dgt;
        const float a3 = cg[s3] + dgt;
        const float x0 = __bfloat162float(A16[(size_t)s0 * 64 + d]);
        const float x1 = __bfloat162float(A16[(size_t)s1 * 64 + d]);
        const float x2 = __bfloat162float(A16[(size_t)s2 * 64 + d]);
        const float x3 = __bfloat162float(A16[(size_t)s3 * 64 + d]);
        acc = fmaf(fmaxf(x0 + Bt, 0.f), a0, acc);
        acc = fmaf(fmaxf(x1 + Bt, 0.f), a1, acc);
        acc = fmaf(fmaxf(x2 + Bt, 0.f), a2, acc);
        acc = fmaf(fmaxf(x3 + Bt, 0.f), a3, acc);
        asum += (a0 + a1) + (a2 + a3);
    }
    for (; e < e1; ++e) {
        const int s   = sorted_src[e];
        const float a = cg[s] + dgt;
        const float xv = __bfloat162float(A16[(size_t)s * 64 + d]);
        acc = fmaf(fmaxf(xv + Bt, 0.f), a, acc);
        asum += a;
    }
    out[(size_t)node * 64 + d] = acc / (asum + 1e-6f);
}

extern "C" void kernel_launch(void* const* d_in, const int* in_sizes, int n_in,
                              void* d_out, int out_size, void* d_ws, size_t ws_size,
                              hipStream_t stream)
{
    // setup_inputs order: x, adj, src, tgt, Msrc, Wf, bf, Ww, bw
    const float* x   = (const float*)d_in[0];
    const int*   src = (const int*)d_in[2];
    const int*   tgt = (const int*)d_in[3];
    const float* Wf  = (const float*)d_in[5];
    const float* bf  = (const float*)d_in[6];
    const float* Ww  = (const float*)d_in[7];
    const float* bw  = (const float*)d_in[8];

    const int N = in_sizes[0] / 64;
    const int E = in_sizes[2];
    float* out = (float*)d_out;

    const int NB    = (N + 255) >> 8;           // 196 buckets (<=256 required)
    const int chunk = (E + NBLK - 1) / NBLK;    // 4000 edges per hist/part block
    const int NBNB  = NB * NBLK;                // 39200 counts

    // pairs (E int2 = 6.4 MB) live in d_out (12.8 MB): fully consumed by
    // gat_bucket_sort before gat_gather writes out. Stream order guarantees it.
    int2* pairs = (int2*)d_out;

    __hip_bfloat16* A16 = (__hip_bfloat16*)d_ws;          // N*64 bf16 (6.4 MB)
    float* B          = (float*)(A16 + (size_t)N * 64);   // N*64 f32  (12.8 MB)
    float* cg         = B + (size_t)N * 64;               // N
    float* dg         = cg + N;                           // N
    int*   starts     = (int*)(dg + N);                   // N+1
    int*   sorted_src = starts + N + 1;                   // E
    int*   counts     = sorted_src + E;                   // NBNB (157 KB)
    int*   bsum       = counts + NBNB;                    // <=1024
    // total ws: ~23.3 MB (same budget as R4, proven to fit)

    const int nb1 = (N + 63) / 64;
    gat_pre_hist<<<nb1 + NBLK, 256, 0, stream>>>(x, Wf, Ww, bf, bw, A16, B, cg, dg, N,
                                                 tgt, counts, E, NB, chunk, nb1);
    const int nbs = (NBNB + 255) / 256;   // 154 <= 1024
    gat_scan1<<<nbs, 256, 0, stream>>>(counts, counts, bsum, NBNB);
    gat_scan2<<<1, 1024, 0, stream>>>(bsum, nbs);
    gat_scan3<<<nbs, 256, 0, stream>>>(counts, bsum, NBNB);
    gat_partition<<<NBLK, 256, 0, stream>>>(src, tgt, counts, pairs, E, NB, chunk);
    gat_bucket_sort<<<NB, 256, 0, stream>>>(pairs, counts, starts, sorted_src, N, E, NB);
    const int nb2 = (N + 3) / 4;  // 4 waves (nodes) per 256-thread block
    gat_gather<<<nb2, 256, 0, stream>>>(starts, sorted_src, A16, B, cg, dg, out, N);
}

// Round 8
// 88.462 us; speedup vs baseline: 3.5167x; 1.0816x over previous
//
#include <hip/hip_runtime.h>
#include <hip/hip_bf16.h>

// GAT edge-average forward, factored + CSR via atomic-free bucketed counting sort:
//   A = x @ Wf[:, :64]^T            [N,64]  bf16 in ws
//   B = x @ Wf[:, 64:]^T + bf       [N,64]  f32 in ws
//   c = x @ Ww[0, :64]              [N]
//   d = x @ Ww[0, 64:] + bw         [N]
//   CSR build (no global atomics):
//     hist:   counts[bucket][blk] via LDS histogram (bucket = tgt>>8, NB=196)
//     scan:   2-phase exclusive scan (block offsets folded into consumers)
//     part:   packed (src<<8 | tgt&255) scattered to bucket regions (in d_out)
//     bsort:  per-bucket LDS counting sort -> starts[], sorted_src[]
//   gather: wave=node, lane=dim, unroll x8: acc += relu(A[s]+B[t])*(c[s]+d[t])

#define NBLK 200   // edge-chunk blocks for hist/partition

__global__ __launch_bounds__(256) void gat_pre_hist(
    const float* __restrict__ x, const float* __restrict__ Wf,
    const float* __restrict__ Ww, const float* __restrict__ bf,
    const float* __restrict__ bw,
    __hip_bfloat16* __restrict__ A16, float* __restrict__ B,
    float* __restrict__ cg, float* __restrict__ dg, int N,
    const int* __restrict__ tgt, int* __restrict__ counts,
    int E, int NB, int chunk, int nb1)
{
    __shared__ float w2[64][132];
    __shared__ float xs[64][68];
    __shared__ float ww[128];
    __shared__ float bfs[64];
    __shared__ int   h[256];

    const int tid = threadIdx.x;

    if (blockIdx.x >= nb1) {
        // LDS-histogram of tgt buckets for this edge chunk; plain global writes
        const int k = blockIdx.x - nb1;          // 0..NBLK-1
        h[tid] = 0;
        __syncthreads();
        const int lo = k * chunk;
        const int hi = min(lo + chunk, E);
        for (int e = lo + tid; e < hi; e += 256)
            atomicAdd(&h[tgt[e] >> 8], 1);       // LDS atomic
        __syncthreads();
        if (tid < NB) counts[tid * NBLK + k] = h[tid];
        return;
    }

    for (int f = tid; f < 64 * 128; f += 256) {
        int d  = f >> 7;
        int kk = f & 127;
        w2[kk & 63][(kk >> 6) * 64 + d] = Wf[f];
    }
    if (tid < 128) ww[tid] = Ww[tid];
    if (tid < 64)  bfs[tid] = bf[tid];

    const int n0 = blockIdx.x << 6;
    for (int i = tid; i < 64 * 64; i += 256) {
        int nl = i >> 6, k = i & 63;
        int n = n0 + nl;
        xs[k][nl] = (n < N) ? x[(size_t)n * 64 + k] : 0.f;
    }
    __syncthreads();

    const int ti = tid & 15, tj = tid >> 4;
    float acc[4][8];
#pragma unroll
    for (int i = 0; i < 4; ++i)
#pragma unroll
        for (int j = 0; j < 8; ++j) acc[i][j] = 0.f;

#pragma unroll 4
    for (int k = 0; k < 64; ++k) {
        const float4 xv = *(const float4*)&xs[k][ti * 4];
        const float4 w0 = *(const float4*)&w2[k][tj * 8];
        const float4 w1 = *(const float4*)&w2[k][tj * 8 + 4];
        const float xa[4] = {xv.x, xv.y, xv.z, xv.w};
        const float wa[8] = {w0.x, w0.y, w0.z, w0.w, w1.x, w1.y, w1.z, w1.w};
#pragma unroll
        for (int i = 0; i < 4; ++i)
#pragma unroll
            for (int j = 0; j < 8; ++j)
                acc[i][j] = fmaf(xa[i], wa[j], acc[i][j]);
    }

#pragma unroll
    for (int i = 0; i < 4; ++i) {
        const int n = n0 + ti * 4 + i;
        if (n < N) {
            if (tj < 8) {
#pragma unroll
                for (int j = 0; j < 8; ++j)
                    A16[(size_t)n * 64 + tj * 8 + j] = __float2bfloat16(acc[i][j]);
            } else {
#pragma unroll
                for (int j = 0; j < 8; ++j) {
                    int d2 = (tj - 8) * 8 + j;
                    B[(size_t)n * 64 + d2] = acc[i][j] + bfs[d2];
                }
            }
        }
    }

    if (tid < 64) {
        const int n = n0 + tid;
        if (n < N) {
            float sc = 0.f, sd = 0.f;
            for (int k = 0; k < 64; ++k) {
                const float xv = xs[k][tid];
                sc = fmaf(xv, ww[k], sc);
                sd = fmaf(xv, ww[64 + k], sd);
            }
            cg[n] = sc;
            dg[n] = sd + bw[0];
        }
    }
}

// Phase 1: per-block exclusive scan (in -> out, may alias), block total -> bsum
__global__ __launch_bounds__(256) void gat_scan1(
    const int* __restrict__ in, int* __restrict__ out,
    int* __restrict__ bsum, int n)
{
    __shared__ int tmp[256];
    const int i = blockIdx.x * 256 + threadIdx.x;
    const int v = (i < n) ? in[i] : 0;
    tmp[threadIdx.x] = v;
    __syncthreads();
#pragma unroll
    for (int off = 1; off < 256; off <<= 1) {
        const int add = (threadIdx.x >= off) ? tmp[threadIdx.x - off] : 0;
        __syncthreads();
        tmp[threadIdx.x] += add;
        __syncthreads();
    }
    if (i < n) out[i] = tmp[threadIdx.x] - v;
    if (threadIdx.x == 255) bsum[blockIdx.x] = tmp[255];
}

// Phase 2: single-block exclusive scan of the <=1024 block sums, in place
__global__ __launch_bounds__(1024) void gat_scan2(int* __restrict__ bsum, int nb)
{
    __shared__ int tmp[1024];
    const int v = (threadIdx.x < nb) ? bsum[threadIdx.x] : 0;
    tmp[threadIdx.x] = v;
    __syncthreads();
#pragma unroll
    for (int off = 1; off < 1024; off <<= 1) {
        const int add = (threadIdx.x >= off) ? tmp[threadIdx.x - off] : 0;
        __syncthreads();
        tmp[threadIdx.x] += add;
        __syncthreads();
    }
    if (threadIdx.x < nb) bsum[threadIdx.x] = tmp[threadIdx.x] - v;
}

// Partition edges into tgt-buckets; psum = counts[i] + bsum[i>>8] (scan3 folded).
// Packed pair: (src << 8) | (tgt & 255). LDS cursors only.
__global__ __launch_bounds__(256) void gat_partition(
    const int* __restrict__ src, const int* __restrict__ tgt,
    const int* __restrict__ counts, const int* __restrict__ bsum,
    unsigned int* __restrict__ pairs, int E, int NB, int chunk)
{
    __shared__ int cur[256];
    const int k = blockIdx.x;
    const int tid = threadIdx.x;
    if (tid < NB) {
        const int idx = tid * NBLK + k;
        cur[tid] = counts[idx] + bsum[idx >> 8];
    }
    __syncthreads();
    const int lo = k * chunk;
    const int hi = min(lo + chunk, E);
    for (int e = lo + tid; e < hi; e += 256) {
        const int t = tgt[e];
        const int s = src[e];
        const int pos = atomicAdd(&cur[t >> 8], 1);   // LDS atomic
        pairs[pos] = ((unsigned int)s << 8) | (unsigned int)(t & 255);
    }
}

// Per-bucket counting sort: block = bucket of 256 consecutive tgt values.
// Emits starts[] (global CSR offsets) and sorted_src[] (contiguous window).
__global__ __launch_bounds__(256) void gat_bucket_sort(
    const unsigned int* __restrict__ pairs, const int* __restrict__ counts,
    const int* __restrict__ bsum,
    int* __restrict__ starts, int* __restrict__ sorted_src,
    int N, int E, int NB)
{
    __shared__ int h[256];
    __shared__ int cur[256];
    const int b = blockIdx.x;
    const int tid = threadIdx.x;
    const int i0 = b * NBLK;
    const int base = counts[i0] + bsum[i0 >> 8];
    int end = E;
    if (b + 1 < NB) {
        const int i1 = (b + 1) * NBLK;
        end = counts[i1] + bsum[i1 >> 8];
    }

    h[tid] = 0;
    __syncthreads();
    for (int e = base + tid; e < end; e += 256)
        atomicAdd(&h[pairs[e] & 255u], 1);            // LDS atomic
    __syncthreads();
    const int v = h[tid];
#pragma unroll
    for (int off = 1; off < 256; off <<= 1) {
        const int add = (tid >= off) ? h[tid - off] : 0;
        __syncthreads();
        h[tid] += add;
        __syncthreads();
    }
    const int excl = h[tid] - v;                      // exclusive within bucket
    const int node = (b << 8) + tid;
    if (node < N) starts[node] = base + excl;
    if (b == NB - 1 && tid == 0) starts[N] = E;
    cur[tid] = base + excl;
    __syncthreads();
    for (int e = base + tid; e < end; e += 256) {
        const unsigned int p = pairs[e];
        const int pos = atomicAdd(&cur[p & 255u], 1); // LDS atomic
        sorted_src[pos] = (int)(p >> 8);
    }
}

__global__ __launch_bounds__(256) void gat_gather(
    const int* __restrict__ starts, const int* __restrict__ sorted_src,
    const __hip_bfloat16* __restrict__ A16, const float* __restrict__ B,
    const float* __restrict__ cg, const float* __restrict__ dg,
    float* __restrict__ out, int N)
{
    const int d = threadIdx.x & 63;
    const int node = blockIdx.x * (blockDim.x >> 6) + (threadIdx.x >> 6);
    if (node >= N) return;
    const int e0 = starts[node];
    const int e1 = starts[node + 1];
    const float Bt  = B[(size_t)node * 64 + d];
    const float dgt = dg[node];
    float acc = 0.f, asum = 0.f;

    int e = e0;
    // unroll x8: 8 independent gather chains in flight per wave
    for (; e + 7 < e1; e += 8) {
        int s[8];
#pragma unroll
        for (int u = 0; u < 8; ++u) s[u] = sorted_src[e + u];
        float a[8], xv[8];
#pragma unroll
        for (int u = 0; u < 8; ++u) a[u] = cg[s[u]] + dgt;
#pragma unroll
        for (int u = 0; u < 8; ++u)
            xv[u] = __bfloat162float(A16[(size_t)s[u] * 64 + d]);
#pragma unroll
        for (int u = 0; u < 8; ++u) {
            acc = fmaf(fmaxf(xv[u] + Bt, 0.f), a[u], acc);
            asum += a[u];
        }
    }
    for (; e + 3 < e1; e += 4) {
        const int s0 = sorted_src[e];
        const int s1 = sorted_src[e + 1];
        const int s2 = sorted_src[e + 2];
        const int s3 = sorted_src[e + 3];
        const float a0 = cg[s0] + dgt;
        const float a1 = cg[s1] + dgt;
        const float a2 = cg[s2] + dgt;
        const float a3 = cg[s3] + dgt;
        const float x0 = __bfloat162float(A16[(size_t)s0 * 64 + d]);
        const float x1 = __bfloat162float(A16[(size_t)s1 * 64 + d]);
        const float x2 = __bfloat162float(A16[(size_t)s2 * 64 + d]);
        const float x3 = __bfloat162float(A16[(size_t)s3 * 64 + d]);
        acc = fmaf(fmaxf(x0 + Bt, 0.f), a0, acc);
        acc = fmaf(fmaxf(x1 + Bt, 0.f), a1, acc);
        acc = fmaf(fmaxf(x2 + Bt, 0.f), a2, acc);
        acc = fmaf(fmaxf(x3 + Bt, 0.f), a3, acc);
        asum += (a0 + a1) + (a2 + a3);
    }
    for (; e < e1; ++e) {
        const int s   = sorted_src[e];
        const float a = cg[s] + dgt;
        const float xv = __bfloat162float(A16[(size_t)s * 64 + d]);
        acc = fmaf(fmaxf(xv + Bt, 0.f), a, acc);
        asum += a;
    }
    out[(size_t)node * 64 + d] = acc / (asum + 1e-6f);
}

extern "C" void kernel_launch(void* const* d_in, const int* in_sizes, int n_in,
                              void* d_out, int out_size, void* d_ws, size_t ws_size,
                              hipStream_t stream)
{
    // setup_inputs order: x, adj, src, tgt, Msrc, Wf, bf, Ww, bw
    const float* x   = (const float*)d_in[0];
    const int*   src = (const int*)d_in[2];
    const int*   tgt = (const int*)d_in[3];
    const float* Wf  = (const float*)d_in[5];
    const float* bf  = (const float*)d_in[6];
    const float* Ww  = (const float*)d_in[7];
    const float* bw  = (const float*)d_in[8];

    const int N = in_sizes[0] / 64;
    const int E = in_sizes[2];
    float* out = (float*)d_out;

    const int NB    = (N + 255) >> 8;           // 196 buckets (<=256 required)
    const int chunk = (E + NBLK - 1) / NBLK;    // 4000 edges per hist/part block
    const int NBNB  = NB * NBLK;                // 39200 counts

    // packed pairs (E u32 = 3.2 MB) live in d_out (12.8 MB): fully consumed by
    // gat_bucket_sort before gat_gather writes out. Stream order guarantees it.
    unsigned int* pairs = (unsigned int*)d_out;

    __hip_bfloat16* A16 = (__hip_bfloat16*)d_ws;          // N*64 bf16 (6.4 MB)
    float* B          = (float*)(A16 + (size_t)N * 64);   // N*64 f32  (12.8 MB)
    float* cg         = B + (size_t)N * 64;               // N
    float* dg         = cg + N;                           // N
    int*   starts     = (int*)(dg + N);                   // N+1
    int*   sorted_src = starts + N + 1;                   // E
    int*   counts     = sorted_src + E;                   // NBNB (157 KB)
    int*   bsum       = counts + NBNB;                    // <=1024
    // total ws: ~23.3 MB

    const int nb1 = (N + 63) / 64;
    gat_pre_hist<<<nb1 + NBLK, 256, 0, stream>>>(x, Wf, Ww, bf, bw, A16, B, cg, dg, N,
                                                 tgt, counts, E, NB, chunk, nb1);
    const int nbs = (NBNB + 255) / 256;   // 154 <= 1024
    gat_scan1<<<nbs, 256, 0, stream>>>(counts, counts, bsum, NBNB);
    gat_scan2<<<1, 1024, 0, stream>>>(bsum, nbs);
    gat_partition<<<NBLK, 256, 0, stream>>>(src, tgt, counts, bsum, pairs, E, NB, chunk);
    gat_bucket_sort<<<NB, 256, 0, stream>>>(pairs, counts, bsum, starts, sorted_src, N, E, NB);
    const int nb2 = (N + 3) / 4;  // 4 waves (nodes) per 256-thread block
    gat_gather<<<nb2, 256, 0, stream>>>(starts, sorted_src, A16, B, cg, dg, out, N);
}